// Round 4
// baseline (457.896 us; speedup 1.0000x reference)
//
#include <hip/hip_runtime.h>
#include <stdint.h>

typedef unsigned int u32;
typedef unsigned long long u64;
typedef unsigned short u16;
typedef unsigned short ushort_t;
typedef short bf16x8 __attribute__((ext_vector_type(8)));
typedef float f32x4  __attribute__((ext_vector_type(4)));

// Problem constants
#define NQ    8192
#define DIMK  256
#define NE    16384
#define CSTR  1024
#define BSTR  262144

#define SLOTS 128
#define CMARG 2.5e-4f   // np tie window (~9e-5) + 2x worst-case bf16 rnd error

// ws layout (bytes): total 10,649,856 <= 10,682,624 proven in round 4
#define WS_EE    256        // float ee[16384]
#define WS_ZZ    65792      // float zz[8192]
#define WS_GMIN  98560      // u32 gmin[8192]
#define WS_CNT   131328     // u32 cnt[8192]
#define WS_CAND  164096     // u16 cand[8192*128] = 2 MB
#define WS_EP    2261248    // ushort Ep[16384*256] = 8 MB (permuted bf16 E)

// fmap(FLT_MAX): finite sentinel for rowthr — funmap() of it is FLT_MAX, NOT NaN.
#define THR_INIT 0xFF7FFFFFu

__device__ __forceinline__ u32 fmap(float f) {
    union { float f; u32 u; } x; x.f = f;
    return (x.u & 0x80000000u) ? ~x.u : (x.u | 0x80000000u);
}
__device__ __forceinline__ float funmap(u32 u) {
    union { float f; u32 u; } x;
    x.u = (u & 0x80000000u) ? (u ^ 0x80000000u) : ~u;
    return x.f;
}
// pack two fp32 -> two bf16 (round-half-up; error budget covered by CMARG, proven R4-R7)
__device__ __forceinline__ u32 pkbf(float lo, float hi) {
    u32 a = __float_as_uint(lo) + 0x8000u;
    u32 b = __float_as_uint(hi) + 0x8000u;
    return __builtin_amdgcn_perm(b, a, 0x07060302u);
}

// ---- numpy einsum dot replica: SSE baseline (W=4, no FMA) — validated R3-R7 ----
__device__ __forceinline__ float np_einsum_dot(const float* __restrict__ zr, int zstride,
                                               const float* __restrict__ er) {
    float a0 = 0.0f, a1 = 0.0f, a2 = 0.0f, a3 = 0.0f;
    for (int s = 0; s < 64; ++s) {
        const int k = s * 4;
        a0 = __fadd_rn(a0, __fmul_rn(zr[(size_t)(k + 0) * zstride], er[k + 0]));
        a1 = __fadd_rn(a1, __fmul_rn(zr[(size_t)(k + 1) * zstride], er[k + 1]));
        a2 = __fadd_rn(a2, __fmul_rn(zr[(size_t)(k + 2) * zstride], er[k + 2]));
        a3 = __fadd_rn(a3, __fmul_rn(zr[(size_t)(k + 3) * zstride], er[k + 3]));
    }
    return __fadd_rn(__fadd_rn(a0, a1), __fadd_rn(a2, a3));
}

// blocks 0..1023: E rows (ee + Ep permuted-bf16 conversion)
// blocks 1024..1055: z rows — R4: COALESCED zz (1 thread per q, linear-k wave loads,
// bitwise np pairwise: 16 accumulators in i-order + index-ordered binary tree ==
// the old 16-lane + shfl-xor tree, add-for-add).
__global__ __launch_bounds__(256)
void k_prep(const float* __restrict__ z, const float* __restrict__ E,
            float* __restrict__ ee, float* __restrict__ zz,
            u32* __restrict__ gmin, u32* __restrict__ cnt, float* __restrict__ acc,
            ushort_t* __restrict__ Ep) {
    const int t = threadIdx.x;
    const int bid = blockIdx.x;
    if (bid == 0 && t == 0) *acc = 0.0f;
    if (bid < 1024) {
        // ---- ee for 16 E rows (np pairwise, 16 lanes/row — unchanged) ----
        const int g = t >> 4, s = t & 15;
        const int row = bid * 16 + g;
        const float* p = E + (size_t)row * DIMK;
        const int h = s >> 3, j = s & 7;
        const float* pp = p + (h * 128 + j);
        float v = pp[0];
        float r = __fmul_rn(v, v);
        for (int i = 1; i < 16; ++i) {
            v = pp[i * 8];
            r = __fadd_rn(r, __fmul_rn(v, v));
        }
        r = __fadd_rn(r, __shfl_xor(r, 1, 16));
        r = __fadd_rn(r, __shfl_xor(r, 2, 16));
        r = __fadd_rn(r, __shfl_xor(r, 4, 16));
        r = __fadd_rn(r, __shfl_xor(r, 8, 16));
        if (s == 0) ee[row] = r;
        // ---- Ep: chunk c = kc*64 + quad*16 + l15 holds bf16 E[bid*16+l15][kc*32+quad*8 .. +7]
#pragma unroll
        for (int i = 0; i < 2; ++i) {
            const int c    = t + i * 256;
            const int kc   = c >> 6;
            const int lane = c & 63;
            const int quad = lane >> 4, l15 = lane & 15;
            const float* src = E + (size_t)(bid * 16 + l15) * DIMK + kc * 32 + quad * 8;
            float4 f0 = *(const float4*)(src);
            float4 f1 = *(const float4*)(src + 4);
            uint4 pk;
            pk.x = pkbf(f0.x, f0.y); pk.y = pkbf(f0.z, f0.w);
            pk.z = pkbf(f1.x, f1.y); pk.w = pkbf(f1.z, f1.w);
            *(uint4*)((char*)Ep + (size_t)bid * 8192 + (size_t)c * 16) = pk;
        }
    } else {
        // ---- zz, coalesced: q = (bid-1024)*256 + t; 64-lane coalesced loads per k ----
        const int q = ((bid - 1024) << 8) | t;
        gmin[q] = 0xFFFFFFFFu;
        cnt[q]  = 0u;
        const int b = q >> 10, hw = q & 1023;
        const float* zb = z + (size_t)b * BSTR + hw;
        // accumulator s=(h<<3)|j sums elements k=h*128+j+i*8, i ascending (np order)
        float a[16];
#pragma unroll 16
        for (int k = 0; k < 256; ++k) {
            const float v  = zb[(size_t)k * CSTR];
            const int  s16 = ((k >> 7) << 3) | (k & 7);
            const float p2 = __fmul_rn(v, v);
            if ((k & 127) < 8) a[s16] = p2;
            else               a[s16] = __fadd_rn(a[s16], p2);
        }
        // index-ordered binary tree == shfl-xor(1,2,4,8) tree at lane 0
        float b1[8], c1[4], d1[2];
#pragma unroll
        for (int m = 0; m < 8; ++m) b1[m] = __fadd_rn(a[2 * m], a[2 * m + 1]);
#pragma unroll
        for (int m = 0; m < 4; ++m) c1[m] = __fadd_rn(b1[2 * m], b1[2 * m + 1]);
#pragma unroll
        for (int m = 0; m < 2; ++m) d1[m] = __fadd_rn(c1[2 * m], c1[2 * m + 1]);
        zz[q] = __fadd_rn(d1[0], d1[1]);
    }
}

// MFMA filter, R4: R3 retile (8 waves x 64x32, 512 thr, 4 waves/SIMD) + HALF-RESIDENT A:
// af for kc 0..3 loaded into registers once per block (64 VGPR), kc 4..7 read from LDS
// per kc as before. Halves sweep DS-pipe traffic (4352 -> 2176 b128/block), which the
// R3 counters showed as the largest single pipe consumer (~37-45% DS busy). VGPR
// budget ~124 under the __launch_bounds__(512,4) cap of 128. Semantics unchanged.
__global__ __launch_bounds__(512, 4)
void k_filter(const float* __restrict__ z, const ushort_t* __restrict__ Ep,
              const float* __restrict__ ee,
              u32* __restrict__ gmin, u32* __restrict__ cnt, u16* __restrict__ cand) {
    __shared__ ushort_t Az[32768];          // 64 KB A store, live across whole sweep
    __shared__ u32 rowthr[128];
    char* lds = (char*)Az;

    const int t     = threadIdx.x;
    const int bid   = blockIdx.x;
    const int chunk = bid & 7;
    const int rb    = bid >> 3;
    const int n0    = rb * 128;
    const int j0c   = chunk * 2048;
    const int b     = n0 >> 10, hw0 = n0 & 1023;
    const int w     = t >> 6, lane = t & 63, quad = lane >> 4, l15 = lane & 15;
    const int wr    = (w >> 2) * 64;        // row-group: waves 0-3 -> rows 0-63, 4-7 -> 64-127
    const int wc    = (w & 3) * 32;         // col-group: 4 groups x 32 cols

    if (t < 128) rowthr[t] = THR_INIT;      // finite sentinel (see THR_INIT note)

    // ---- stage A once: z[b][k][hw] -> bf16 LDS [row][k] swizzled (unchanged) ----
    {
        const int rbase = (t & 31) * 4;
        const int ksub  = (t >> 5) * 2;     // 16 values: 0,2,...,30
        for (int p = 0; p < 8; ++p) {
            const int k0 = p * 32 + ksub;
            float4 f0 = *(const float4*)(z + (size_t)b * BSTR + (size_t)k0 * CSTR + hw0 + rbase);
            float4 f1 = *(const float4*)(z + (size_t)b * BSTR + (size_t)(k0 + 1) * CSTR + hw0 + rbase);
            const float a0[4] = {f0.x, f0.y, f0.z, f0.w};
            const float a1[4] = {f1.x, f1.y, f1.z, f1.w};
#pragma unroll
            for (int i = 0; i < 4; ++i) {
                const int row = rbase + i;
                *(u32*)(lds + row * 512 + ((k0 * 2) ^ ((row & 7) << 4))) = pkbf(a0[i], a1[i]);
            }
        }
    }
    __syncthreads();   // only barrier — sweep below is barrier-free; Az persists

    // per-wave A row addressing (fi-indexed, fully unrolled -> static)
    int aoff[4], aswz[4];
#pragma unroll
    for (int fi = 0; fi < 4; ++fi) {
        const int row = wr + fi * 16 + l15;
        aoff[fi] = row * 512;
        aswz[fi] = (row & 7) << 4;
    }

    // half-resident A: kc 0..3 in registers, loaded once (16x ds_read_b128)
    bf16x8 afr[4][4];
#pragma unroll
    for (int fi = 0; fi < 4; ++fi)
#pragma unroll
        for (int kc = 0; kc < 4; ++kc)
            afr[fi][kc] = *(const bf16x8*)(lds + aoff[fi] + ((kc * 64 + quad * 16) ^ aswz[fi]));

    const int cbase = (j0c + wc) >> 4;   // 16-col group index of fj=0, tile 0 ref
    const size_t lofs = (size_t)lane * 8;

    bf16x8 bufA[2], bufB[2];
#define LOADB(dst, ct, kc)                                                        \
    {                                                                             \
        const int bg = cbase + (ct) * 8;                                          \
        const size_t ko = (size_t)((kc) * 64) * 8 + lofs;                         \
        _Pragma("unroll")                                                         \
        for (int fj = 0; fj < 2; ++fj)                                            \
            dst[fj] = *(const bf16x8*)(Ep + (size_t)(bg + fj) * 4096 + ko);       \
    }

    LOADB(bufA, 0, 0);   // prime the pipeline

    // sweep tiles; it==16 re-visits tile 0 with tight thresholds (bootstrap)
    for (int it = 0; it <= 16; ++it) {
        const int ct = (it == 16) ? 0 : it;
        const bool collect = (it > 0);
        const int j0 = j0c + ct * 128;

        float eev[2];
#pragma unroll
        for (int fj = 0; fj < 2; ++fj) eev[fj] = ee[j0 + wc + fj * 16 + l15];

        f32x4 acc[4][2];
#pragma unroll
        for (int fi = 0; fi < 4; ++fi)
#pragma unroll
            for (int fj = 0; fj < 2; ++fj)
#pragma unroll
                for (int r = 0; r < 4; ++r) acc[fi][fj][r] = 0.0f;

#pragma unroll
        for (int kc = 0; kc < 8; ++kc) {
            // issue next buffer's loads BEFORE consuming current (stay in flight)
            int nit = it, nkc = kc + 1;
            if (nkc == 8) { nkc = 0; nit = it + 1; }
            const int nct = (nit >= 16) ? 0 : nit;
            // A fragments: kc<4 from resident registers; kc>=4 from LDS (2-way = free)
            bf16x8 afk[4];
            if (kc < 4) {
#pragma unroll
                for (int fi = 0; fi < 4; ++fi) afk[fi] = afr[fi][kc];
            } else {
#pragma unroll
                for (int fi = 0; fi < 4; ++fi)
                    afk[fi] = *(const bf16x8*)(lds + aoff[fi] + ((kc * 64 + quad * 16) ^ aswz[fi]));
            }
            if (kc & 1) {
                LOADB(bufA, nct, nkc);
#pragma unroll
                for (int fi = 0; fi < 4; ++fi)
#pragma unroll
                    for (int fj = 0; fj < 2; ++fj)
                        acc[fi][fj] = __builtin_amdgcn_mfma_f32_16x16x32_bf16(
                            afk[fi], bufB[fj], acc[fi][fj], 0, 0, 0);
            } else {
                LOADB(bufB, nct, nkc);
#pragma unroll
                for (int fi = 0; fi < 4; ++fi)
#pragma unroll
                    for (int fj = 0; fj < 2; ++fj)
                        acc[fi][fj] = __builtin_amdgcn_mfma_f32_16x16x32_bf16(
                            afk[fi], bufA[fj], acc[fi][fj], 0, 0, 0);
            }
        }

        // ---- any-skip epilogue (R0-exact semantics): v = ee - 2*dot ----
#pragma unroll
        for (int fi = 0; fi < 4; ++fi) {
#pragma unroll
            for (int r = 0; r < 4; ++r) {
                const float vv0 = fmaf(-2.0f, acc[fi][0][r], eev[0]);
                const float vv1 = fmaf(-2.0f, acc[fi][1][r], eev[1]);
                const float lmin = fminf(vv0, vv1);
                const int rl = wr + fi * 16 + quad * 4 + r;
                const u32 pre = rowthr[rl];                 // history BEFORE own update
                const float thr = funmap(pre) + CMARG;      // finite (THR_INIT sentinel)
                // skip-safe: no lane <= thr => no collect AND wave-min > pre (atomic no-op)
                if (__any(lmin <= thr)) {
                    float m = lmin;
                    m = fminf(m, __shfl_xor(m, 1, 16));
                    m = fminf(m, __shfl_xor(m, 2, 16));
                    m = fminf(m, __shfl_xor(m, 4, 16));
                    m = fminf(m, __shfl_xor(m, 8, 16));
                    if (l15 == 0) atomicMin(&rowthr[rl], fmap(m));
                    if (collect) {
                        // pre >= global row min => thr complete for the np winner
                        const int rg = n0 + rl;
                        if (vv0 <= thr) {
                            u32 p = atomicAdd(&cnt[rg], 1u);
                            if (p < SLOTS)
                                cand[(size_t)rg * SLOTS + p] = (u16)(j0 + wc + l15);
                        }
                        if (vv1 <= thr) {
                            u32 p = atomicAdd(&cnt[rg], 1u);
                            if (p < SLOTS)
                                cand[(size_t)rg * SLOTS + p] = (u16)(j0 + wc + 16 + l15);
                        }
                    }
                }
            }
        }
        // every-tile cross-chunk threshold exchange (R0-exact: monotone-safe, no barrier)
        if (t < 128) {
            const u32 lv = rowthr[t];
            const u32 old = atomicMin(&gmin[n0 + t], lv);
            if (old < lv) atomicMin(&rowthr[t], old);
        }
    }
#undef LOADB
}

// numpy-bitwise rescore of ALL collected candidates (winner provably in set)
__global__ __launch_bounds__(64)
void k_rescore(const float* __restrict__ z, const float* __restrict__ E,
               const float* __restrict__ zz, const float* __restrict__ ee,
               const u32* __restrict__ cnt, const u16* __restrict__ cand,
               float* __restrict__ out_idx) {
    const int q = blockIdx.x;
    const int t = threadIdx.x;
    const int b = q >> 10, hw = q & 1023;
    const u32 n = min(cnt[q], (u32)SLOTS);

    u64 best = 0xFFFFFFFFFFFFFFFFULL;
#pragma unroll
    for (int s = 0; s < 2; ++s) {
        const u32 slot = (u32)t + s * 64;
        if (slot < n) {
            const int j = (int)cand[(size_t)q * SLOTS + slot] & (NE - 1);   // OOB-proof
            const float ze = np_einsum_dot(z + (size_t)b * BSTR + hw, CSTR, E + (size_t)j * DIMK);
            const float t1 = __fadd_rn(zz[q], ee[j]);
            const float d  = __fsub_rn(t1, __fmul_rn(2.0f, ze));
            u64 key = ((u64)fmap(d) << 32) | (u32)j;   // ties -> lowest j
            if (key < best) best = key;
        }
    }
#pragma unroll
    for (int off = 1; off < 64; off <<= 1) {
        u64 o = __shfl_xor(best, off, 64);
        if (o < best) best = o;
    }
    if (t == 0) out_idx[q] = (float)((int)(best & 0xFFFFFFFFULL) & (NE - 1));
}

// gather + loss; R4: 1024 blocks (32 q-groups x 32 c-groups of 8 channels),
// no LDS tile (the old T[t][cc] readback was a register round-trip), 4 blocks/CU.
__global__ __launch_bounds__(256)
void k_finalize(const float* __restrict__ z, const float* __restrict__ E,
                const float* __restrict__ out_idx,
                float* __restrict__ out0, float* __restrict__ acc) {
    __shared__ float red[256];
    const int t  = threadIdx.x;
    const int qg = blockIdx.x >> 5;
    const int ch = blockIdx.x & 31;
    const int q0 = qg * 256;
    const int c0 = ch * 8;
    const int b  = q0 >> 10, hw0 = q0 & 1023;
    const int idx = ((int)out_idx[q0 + t]) & (NE - 1);
    const float* er = E + (size_t)idx * DIMK + c0;
    float4 f0 = *(const float4*)(er);
    float4 f1 = *(const float4*)(er + 4);
    const float ev[8] = {f0.x, f0.y, f0.z, f0.w, f1.x, f1.y, f1.z, f1.w};
    float ls = 0.0f;
#pragma unroll
    for (int cc = 0; cc < 8; ++cc) {
        // output (c0+cc, hw0+t) gets row q=hw0+t's embedding value
        const size_t o = (size_t)b * BSTR + (size_t)(c0 + cc) * CSTR + hw0 + t;
        const float d = ev[cc] - z[o];
        ls = fmaf(d, d, ls);
        out0[o] = ev[cc];
    }
    red[t] = ls;
    __syncthreads();
    for (int s = 128; s > 0; s >>= 1) {
        if (t < s) red[t] += red[t + s];
        __syncthreads();
    }
    if (t == 0) atomicAdd(acc, red[0]);
}

__global__ void k_loss(const float* __restrict__ acc, float* __restrict__ out_loss) {
    *out_loss = 1.25f * (*acc) * (1.0f / 2097152.0f);
}

extern "C" void kernel_launch(void* const* d_in, const int* in_sizes, int n_in,
                              void* d_out, int out_size, void* d_ws, size_t ws_size,
                              hipStream_t stream) {
    const float* z = (const float*)d_in[0];   // [8,256,32,32] fp32
    const float* E = (const float*)d_in[1];   // [16384,256] fp32

    float* out0     = (float*)d_out;
    float* out_loss = (float*)d_out + 2097152;
    float* out_idx  = (float*)d_out + 2097153;

    float*    acc  = (float*)d_ws;
    float*    ee   = (float*)((char*)d_ws + WS_EE);
    float*    zz   = (float*)((char*)d_ws + WS_ZZ);
    u32*      gmin = (u32*)  ((char*)d_ws + WS_GMIN);
    u32*      cnt  = (u32*)  ((char*)d_ws + WS_CNT);
    u16*      cand = (u16*)  ((char*)d_ws + WS_CAND);
    ushort_t* Ep   = (ushort_t*)((char*)d_ws + WS_EP);

    k_prep<<<1056, 256, 0, stream>>>(z, E, ee, zz, gmin, cnt, acc, Ep);
    k_filter<<<512, 512, 0, stream>>>(z, Ep, ee, gmin, cnt, cand);
    k_rescore<<<NQ, 64, 0, stream>>>(z, E, zz, ee, cnt, cand, out_idx);
    k_finalize<<<1024, 256, 0, stream>>>(z, E, out_idx, out0, acc);
    k_loss<<<1, 1, 0, stream>>>(acc, out_loss);
}

// Round 5
// 375.165 us; speedup vs baseline: 1.2205x; 1.2205x over previous
//
#include <hip/hip_runtime.h>
#include <stdint.h>

typedef unsigned int u32;
typedef unsigned long long u64;
typedef unsigned short u16;
typedef unsigned short ushort_t;
typedef short bf16x8 __attribute__((ext_vector_type(8)));
typedef float f32x4  __attribute__((ext_vector_type(4)));

// Problem constants
#define NQ    8192
#define DIMK  256
#define NE    16384
#define CSTR  1024
#define BSTR  262144

#define SLOTS 128
#define CMARG 2.5e-4f   // np tie window (~9e-5) + 2x worst-case bf16 rnd error

// ws layout (bytes): total 10,649,856 <= 10,682,624 proven in round 4
#define WS_EE    256        // float ee[16384]
#define WS_ZZ    65792      // float zz[8192]
#define WS_GMIN  98560      // u32 gmin[8192]
#define WS_CNT   131328     // u32 cnt[8192]
#define WS_CAND  164096     // u16 cand[8192*128] = 2 MB
#define WS_EP    2261248    // ushort Ep[16384*256] = 8 MB (permuted bf16 E)

// fmap(FLT_MAX): finite sentinel for rowthr — funmap() of it is FLT_MAX, NOT NaN.
#define THR_INIT 0xFF7FFFFFu

__device__ __forceinline__ u32 fmap(float f) {
    union { float f; u32 u; } x; x.f = f;
    return (x.u & 0x80000000u) ? ~x.u : (x.u | 0x80000000u);
}
__device__ __forceinline__ float funmap(u32 u) {
    union { float f; u32 u; } x;
    x.u = (u & 0x80000000u) ? (u ^ 0x80000000u) : ~u;
    return x.f;
}
// pack two fp32 -> two bf16 (round-half-up; error budget covered by CMARG, proven R4-R7)
__device__ __forceinline__ u32 pkbf(float lo, float hi) {
    u32 a = __float_as_uint(lo) + 0x8000u;
    u32 b = __float_as_uint(hi) + 0x8000u;
    return __builtin_amdgcn_perm(b, a, 0x07060302u);
}

// ---- numpy einsum dot replica: SSE baseline (W=4, no FMA) — validated R3-R7 ----
__device__ __forceinline__ float np_einsum_dot(const float* __restrict__ zr, int zstride,
                                               const float* __restrict__ er) {
    float a0 = 0.0f, a1 = 0.0f, a2 = 0.0f, a3 = 0.0f;
    for (int s = 0; s < 64; ++s) {
        const int k = s * 4;
        a0 = __fadd_rn(a0, __fmul_rn(zr[(size_t)(k + 0) * zstride], er[k + 0]));
        a1 = __fadd_rn(a1, __fmul_rn(zr[(size_t)(k + 1) * zstride], er[k + 1]));
        a2 = __fadd_rn(a2, __fmul_rn(zr[(size_t)(k + 2) * zstride], er[k + 2]));
        a3 = __fadd_rn(a3, __fmul_rn(zr[(size_t)(k + 3) * zstride], er[k + 3]));
    }
    return __fadd_rn(__fadd_rn(a0, a1), __fadd_rn(a2, a3));
}

// blocks 0..1023: E rows (ee + Ep permuted-bf16 conversion)
// blocks 1024..1055: z rows — coalesced zz (1 thread per q, linear-k wave loads,
// bitwise np pairwise: 16 accumulators in i-order + index-ordered binary tree).
__global__ __launch_bounds__(256)
void k_prep(const float* __restrict__ z, const float* __restrict__ E,
            float* __restrict__ ee, float* __restrict__ zz,
            u32* __restrict__ gmin, u32* __restrict__ cnt, float* __restrict__ acc,
            ushort_t* __restrict__ Ep) {
    const int t = threadIdx.x;
    const int bid = blockIdx.x;
    if (bid == 0 && t == 0) *acc = 0.0f;
    if (bid < 1024) {
        // ---- ee for 16 E rows (np pairwise, 16 lanes/row — unchanged) ----
        const int g = t >> 4, s = t & 15;
        const int row = bid * 16 + g;
        const float* p = E + (size_t)row * DIMK;
        const int h = s >> 3, j = s & 7;
        const float* pp = p + (h * 128 + j);
        float v = pp[0];
        float r = __fmul_rn(v, v);
        for (int i = 1; i < 16; ++i) {
            v = pp[i * 8];
            r = __fadd_rn(r, __fmul_rn(v, v));
        }
        r = __fadd_rn(r, __shfl_xor(r, 1, 16));
        r = __fadd_rn(r, __shfl_xor(r, 2, 16));
        r = __fadd_rn(r, __shfl_xor(r, 4, 16));
        r = __fadd_rn(r, __shfl_xor(r, 8, 16));
        if (s == 0) ee[row] = r;
        // ---- Ep: chunk c = kc*64 + quad*16 + l15 holds bf16 E[bid*16+l15][kc*32+quad*8 .. +7]
#pragma unroll
        for (int i = 0; i < 2; ++i) {
            const int c    = t + i * 256;
            const int kc   = c >> 6;
            const int lane = c & 63;
            const int quad = lane >> 4, l15 = lane & 15;
            const float* src = E + (size_t)(bid * 16 + l15) * DIMK + kc * 32 + quad * 8;
            float4 f0 = *(const float4*)(src);
            float4 f1 = *(const float4*)(src + 4);
            uint4 pk;
            pk.x = pkbf(f0.x, f0.y); pk.y = pkbf(f0.z, f0.w);
            pk.z = pkbf(f1.x, f1.y); pk.w = pkbf(f1.z, f1.w);
            *(uint4*)((char*)Ep + (size_t)bid * 8192 + (size_t)c * 16) = pk;
        }
    } else {
        // ---- zz, coalesced: q = (bid-1024)*256 + t; 64-lane coalesced loads per k ----
        const int q = ((bid - 1024) << 8) | t;
        gmin[q] = 0xFFFFFFFFu;
        cnt[q]  = 0u;
        const int b = q >> 10, hw = q & 1023;
        const float* zb = z + (size_t)b * BSTR + hw;
        // accumulator s=(h<<3)|j sums elements k=h*128+j+i*8, i ascending (np order)
        float a[16];
#pragma unroll 16
        for (int k = 0; k < 256; ++k) {
            const float v  = zb[(size_t)k * CSTR];
            const int  s16 = ((k >> 7) << 3) | (k & 7);
            const float p2 = __fmul_rn(v, v);
            if ((k & 127) < 8) a[s16] = p2;
            else               a[s16] = __fadd_rn(a[s16], p2);
        }
        // index-ordered binary tree == shfl-xor(1,2,4,8) tree at lane 0
        float b1[8], c1[4], d1[2];
#pragma unroll
        for (int m = 0; m < 8; ++m) b1[m] = __fadd_rn(a[2 * m], a[2 * m + 1]);
#pragma unroll
        for (int m = 0; m < 4; ++m) c1[m] = __fadd_rn(b1[2 * m], b1[2 * m + 1]);
#pragma unroll
        for (int m = 0; m < 2; ++m) d1[m] = __fadd_rn(c1[2 * m], c1[2 * m + 1]);
        zz[q] = __fadd_rn(d1[0], d1[1]);
    }
}

// MFMA filter, R5: exact R3 A-path (per-kc LDS reads — R4's register-resident A
// SPILLED: VGPR stayed 64, FETCH 44->596 MB of scratch traffic, 118->244 us).
// New: B-prefetch distance 2 via 4-slot ring buffer (all slot indices
// compile-time after unroll). R3's exposed stall: 1-kc distance covers an
// L2 B-load (~200+ cyc) with only ~16 MFMA (~78 cyc); distance 2 doubles cover.
// VGPR +16 (~80 total), under the (512,4) cap of 128 -> no spill expected.
__global__ __launch_bounds__(512, 4)
void k_filter(const float* __restrict__ z, const ushort_t* __restrict__ Ep,
              const float* __restrict__ ee,
              u32* __restrict__ gmin, u32* __restrict__ cnt, u16* __restrict__ cand) {
    __shared__ ushort_t Az[32768];          // 64 KB A store, live across whole sweep
    __shared__ u32 rowthr[128];
    char* lds = (char*)Az;

    const int t     = threadIdx.x;
    const int bid   = blockIdx.x;
    const int chunk = bid & 7;
    const int rb    = bid >> 3;
    const int n0    = rb * 128;
    const int j0c   = chunk * 2048;
    const int b     = n0 >> 10, hw0 = n0 & 1023;
    const int w     = t >> 6, lane = t & 63, quad = lane >> 4, l15 = lane & 15;
    const int wr    = (w >> 2) * 64;        // row-group: waves 0-3 -> rows 0-63, 4-7 -> 64-127
    const int wc    = (w & 3) * 32;         // col-group: 4 groups x 32 cols

    if (t < 128) rowthr[t] = THR_INIT;      // finite sentinel (see THR_INIT note)

    // ---- stage A once: z[b][k][hw] -> bf16 LDS [row][k] swizzled (unchanged) ----
    {
        const int rbase = (t & 31) * 4;
        const int ksub  = (t >> 5) * 2;     // 16 values: 0,2,...,30
        for (int p = 0; p < 8; ++p) {
            const int k0 = p * 32 + ksub;
            float4 f0 = *(const float4*)(z + (size_t)b * BSTR + (size_t)k0 * CSTR + hw0 + rbase);
            float4 f1 = *(const float4*)(z + (size_t)b * BSTR + (size_t)(k0 + 1) * CSTR + hw0 + rbase);
            const float a0[4] = {f0.x, f0.y, f0.z, f0.w};
            const float a1[4] = {f1.x, f1.y, f1.z, f1.w};
#pragma unroll
            for (int i = 0; i < 4; ++i) {
                const int row = rbase + i;
                *(u32*)(lds + row * 512 + ((k0 * 2) ^ ((row & 7) << 4))) = pkbf(a0[i], a1[i]);
            }
        }
    }
    __syncthreads();   // only barrier — sweep below is barrier-free; Az persists

    // per-wave A row addressing (fi-indexed, fully unrolled -> static)
    int aoff[4], aswz[4];
#pragma unroll
    for (int fi = 0; fi < 4; ++fi) {
        const int row = wr + fi * 16 + l15;
        aoff[fi] = row * 512;
        aswz[fi] = (row & 7) << 4;
    }

    const int cbase = (j0c + wc) >> 4;   // 16-col group index of fj=0, tile 0 ref
    const size_t lofs = (size_t)lane * 8;

    // 4-slot B ring: step s = it*8+kc consumes slot s&3, loaded at step s-2.
    bf16x8 buf[4][2];
#define LOADB(slot, ct, kc)                                                       \
    {                                                                             \
        const int bg = cbase + (ct) * 8;                                          \
        const size_t ko = (size_t)((kc) * 64) * 8 + lofs;                         \
        _Pragma("unroll")                                                         \
        for (int fj = 0; fj < 2; ++fj)                                            \
            buf[slot][fj] = *(const bf16x8*)(Ep + (size_t)(bg + fj) * 4096 + ko); \
    }

    LOADB(0, 0, 0);   // prime: (it0,kc0) -> slot 0
    LOADB(1, 0, 1);   // prime: (it0,kc1) -> slot 1

    // sweep tiles; it==16 re-visits tile 0 with tight thresholds (bootstrap)
    for (int it = 0; it <= 16; ++it) {
        const int ct = (it == 16) ? 0 : it;
        const bool collect = (it > 0);
        const int j0 = j0c + ct * 128;

        float eev[2];
#pragma unroll
        for (int fj = 0; fj < 2; ++fj) eev[fj] = ee[j0 + wc + fj * 16 + l15];

        f32x4 acc[4][2];
#pragma unroll
        for (int fi = 0; fi < 4; ++fi)
#pragma unroll
            for (int fj = 0; fj < 2; ++fj)
#pragma unroll
                for (int r = 0; r < 4; ++r) acc[fi][fj][r] = 0.0f;

#pragma unroll
        for (int kc = 0; kc < 8; ++kc) {
            // issue loads for step kc+2 (distance-2 prefetch, stays in flight
            // across ~32 MFMAs + epilogue slack)
            int nit = it, nkc = kc + 2;
            if (nkc >= 8) { nkc -= 8; nit = it + 1; }
            const int nct = (nit >= 16) ? 0 : nit;
            LOADB((kc + 2) & 3, nct, nkc);
            // A fragments for this kc from LDS (4x ds_read_b128, 2-way conflict = free)
            bf16x8 afk[4];
#pragma unroll
            for (int fi = 0; fi < 4; ++fi)
                afk[fi] = *(const bf16x8*)(lds + aoff[fi] + ((kc * 64 + quad * 16) ^ aswz[fi]));
#pragma unroll
            for (int fi = 0; fi < 4; ++fi)
#pragma unroll
                for (int fj = 0; fj < 2; ++fj)
                    acc[fi][fj] = __builtin_amdgcn_mfma_f32_16x16x32_bf16(
                        afk[fi], buf[kc & 3][fj], acc[fi][fj], 0, 0, 0);
        }

        // ---- any-skip epilogue (R0-exact semantics): v = ee - 2*dot ----
#pragma unroll
        for (int fi = 0; fi < 4; ++fi) {
#pragma unroll
            for (int r = 0; r < 4; ++r) {
                const float vv0 = fmaf(-2.0f, acc[fi][0][r], eev[0]);
                const float vv1 = fmaf(-2.0f, acc[fi][1][r], eev[1]);
                const float lmin = fminf(vv0, vv1);
                const int rl = wr + fi * 16 + quad * 4 + r;
                const u32 pre = rowthr[rl];                 // history BEFORE own update
                const float thr = funmap(pre) + CMARG;      // finite (THR_INIT sentinel)
                // skip-safe: no lane <= thr => no collect AND wave-min > pre (atomic no-op)
                if (__any(lmin <= thr)) {
                    float m = lmin;
                    m = fminf(m, __shfl_xor(m, 1, 16));
                    m = fminf(m, __shfl_xor(m, 2, 16));
                    m = fminf(m, __shfl_xor(m, 4, 16));
                    m = fminf(m, __shfl_xor(m, 8, 16));
                    if (l15 == 0) atomicMin(&rowthr[rl], fmap(m));
                    if (collect) {
                        // pre >= global row min => thr complete for the np winner
                        const int rg = n0 + rl;
                        if (vv0 <= thr) {
                            u32 p = atomicAdd(&cnt[rg], 1u);
                            if (p < SLOTS)
                                cand[(size_t)rg * SLOTS + p] = (u16)(j0 + wc + l15);
                        }
                        if (vv1 <= thr) {
                            u32 p = atomicAdd(&cnt[rg], 1u);
                            if (p < SLOTS)
                                cand[(size_t)rg * SLOTS + p] = (u16)(j0 + wc + 16 + l15);
                        }
                    }
                }
            }
        }
        // every-tile cross-chunk threshold exchange (R0-exact: monotone-safe, no barrier)
        if (t < 128) {
            const u32 lv = rowthr[t];
            const u32 old = atomicMin(&gmin[n0 + t], lv);
            if (old < lv) atomicMin(&rowthr[t], old);
        }
    }
#undef LOADB
}

// numpy-bitwise rescore of ALL collected candidates (winner provably in set)
__global__ __launch_bounds__(64)
void k_rescore(const float* __restrict__ z, const float* __restrict__ E,
               const float* __restrict__ zz, const float* __restrict__ ee,
               const u32* __restrict__ cnt, const u16* __restrict__ cand,
               float* __restrict__ out_idx) {
    const int q = blockIdx.x;
    const int t = threadIdx.x;
    const int b = q >> 10, hw = q & 1023;
    const u32 n = min(cnt[q], (u32)SLOTS);

    u64 best = 0xFFFFFFFFFFFFFFFFULL;
#pragma unroll
    for (int s = 0; s < 2; ++s) {
        const u32 slot = (u32)t + s * 64;
        if (slot < n) {
            const int j = (int)cand[(size_t)q * SLOTS + slot] & (NE - 1);   // OOB-proof
            const float ze = np_einsum_dot(z + (size_t)b * BSTR + hw, CSTR, E + (size_t)j * DIMK);
            const float t1 = __fadd_rn(zz[q], ee[j]);
            const float d  = __fsub_rn(t1, __fmul_rn(2.0f, ze));
            u64 key = ((u64)fmap(d) << 32) | (u32)j;   // ties -> lowest j
            if (key < best) best = key;
        }
    }
#pragma unroll
    for (int off = 1; off < 64; off <<= 1) {
        u64 o = __shfl_xor(best, off, 64);
        if (o < best) best = o;
    }
    if (t == 0) out_idx[q] = (float)((int)(best & 0xFFFFFFFFULL) & (NE - 1));
}

// gather + loss; 1024 blocks (32 q-groups x 32 c-groups of 8 channels),
// no LDS tile, 4 blocks/CU.
__global__ __launch_bounds__(256)
void k_finalize(const float* __restrict__ z, const float* __restrict__ E,
                const float* __restrict__ out_idx,
                float* __restrict__ out0, float* __restrict__ acc) {
    __shared__ float red[256];
    const int t  = threadIdx.x;
    const int qg = blockIdx.x >> 5;
    const int ch = blockIdx.x & 31;
    const int q0 = qg * 256;
    const int c0 = ch * 8;
    const int b  = q0 >> 10, hw0 = q0 & 1023;
    const int idx = ((int)out_idx[q0 + t]) & (NE - 1);
    const float* er = E + (size_t)idx * DIMK + c0;
    float4 f0 = *(const float4*)(er);
    float4 f1 = *(const float4*)(er + 4);
    const float ev[8] = {f0.x, f0.y, f0.z, f0.w, f1.x, f1.y, f1.z, f1.w};
    float ls = 0.0f;
#pragma unroll
    for (int cc = 0; cc < 8; ++cc) {
        // output (c0+cc, hw0+t) gets row q=hw0+t's embedding value
        const size_t o = (size_t)b * BSTR + (size_t)(c0 + cc) * CSTR + hw0 + t;
        const float d = ev[cc] - z[o];
        ls = fmaf(d, d, ls);
        out0[o] = ev[cc];
    }
    red[t] = ls;
    __syncthreads();
    for (int s = 128; s > 0; s >>= 1) {
        if (t < s) red[t] += red[t + s];
        __syncthreads();
    }
    if (t == 0) atomicAdd(acc, red[0]);
}

__global__ void k_loss(const float* __restrict__ acc, float* __restrict__ out_loss) {
    *out_loss = 1.25f * (*acc) * (1.0f / 2097152.0f);
}

extern "C" void kernel_launch(void* const* d_in, const int* in_sizes, int n_in,
                              void* d_out, int out_size, void* d_ws, size_t ws_size,
                              hipStream_t stream) {
    const float* z = (const float*)d_in[0];   // [8,256,32,32] fp32
    const float* E = (const float*)d_in[1];   // [16384,256] fp32

    float* out0     = (float*)d_out;
    float* out_loss = (float*)d_out + 2097152;
    float* out_idx  = (float*)d_out + 2097153;

    float*    acc  = (float*)d_ws;
    float*    ee   = (float*)((char*)d_ws + WS_EE);
    float*    zz   = (float*)((char*)d_ws + WS_ZZ);
    u32*      gmin = (u32*)  ((char*)d_ws + WS_GMIN);
    u32*      cnt  = (u32*)  ((char*)d_ws + WS_CNT);
    u16*      cand = (u16*)  ((char*)d_ws + WS_CAND);
    ushort_t* Ep   = (ushort_t*)((char*)d_ws + WS_EP);

    k_prep<<<1056, 256, 0, stream>>>(z, E, ee, zz, gmin, cnt, acc, Ep);
    k_filter<<<512, 512, 0, stream>>>(z, Ep, ee, gmin, cnt, cand);
    k_rescore<<<NQ, 64, 0, stream>>>(z, E, zz, ee, cnt, cand, out_idx);
    k_finalize<<<1024, 256, 0, stream>>>(z, E, out_idx, out0, acc);
    k_loss<<<1, 1, 0, stream>>>(acc, out_loss);
}

// Round 6
// 266.766 us; speedup vs baseline: 1.7165x; 1.4063x over previous
//
#include <hip/hip_runtime.h>
#include <stdint.h>

typedef unsigned int u32;
typedef unsigned long long u64;
typedef unsigned short u16;
typedef unsigned short ushort_t;
typedef short bf16x8 __attribute__((ext_vector_type(8)));
typedef float f32x4  __attribute__((ext_vector_type(4)));

// Problem constants
#define NQ    8192
#define DIMK  256
#define NE    16384
#define CSTR  1024
#define BSTR  262144

#define SLOTS 128
#define CMARG 2.5e-4f   // np tie window (~9e-5) + 2x worst-case bf16 rnd error

// ws layout (bytes): total 10,649,856 <= 10,682,624 proven in round 4
#define WS_EE    256        // float ee[16384]
#define WS_ZZ    65792      // float zz[8192]
#define WS_GMIN  98560      // u32 gmin[8192]
#define WS_CNT   131328     // u32 cnt[8192]
#define WS_CAND  164096     // u16 cand[8192*128] = 2 MB
#define WS_EP    2261248    // ushort Ep[16384*256] = 8 MB (permuted bf16 E)

// fmap(FLT_MAX): finite sentinel for rowthr — funmap() of it is FLT_MAX, NOT NaN.
#define THR_INIT 0xFF7FFFFFu

__device__ __forceinline__ u32 fmap(float f) {
    union { float f; u32 u; } x; x.f = f;
    return (x.u & 0x80000000u) ? ~x.u : (x.u | 0x80000000u);
}
__device__ __forceinline__ float funmap(u32 u) {
    union { float f; u32 u; } x;
    x.u = (u & 0x80000000u) ? (u ^ 0x80000000u) : ~u;
    return x.f;
}
// pack two fp32 -> two bf16 (round-half-up; error budget covered by CMARG, proven R4-R7)
__device__ __forceinline__ u32 pkbf(float lo, float hi) {
    u32 a = __float_as_uint(lo) + 0x8000u;
    u32 b = __float_as_uint(hi) + 0x8000u;
    return __builtin_amdgcn_perm(b, a, 0x07060302u);
}

// ---- numpy einsum dot replica: SSE baseline (W=4, no FMA) — validated R3-R7 ----
__device__ __forceinline__ float np_einsum_dot(const float* __restrict__ zr, int zstride,
                                               const float* __restrict__ er) {
    float a0 = 0.0f, a1 = 0.0f, a2 = 0.0f, a3 = 0.0f;
    for (int s = 0; s < 64; ++s) {
        const int k = s * 4;
        a0 = __fadd_rn(a0, __fmul_rn(zr[(size_t)(k + 0) * zstride], er[k + 0]));
        a1 = __fadd_rn(a1, __fmul_rn(zr[(size_t)(k + 1) * zstride], er[k + 1]));
        a2 = __fadd_rn(a2, __fmul_rn(zr[(size_t)(k + 2) * zstride], er[k + 2]));
        a3 = __fadd_rn(a3, __fmul_rn(zr[(size_t)(k + 3) * zstride], er[k + 3]));
    }
    return __fadd_rn(__fadd_rn(a0, a1), __fadd_rn(a2, a3));
}

// R6: FULL REVERT to the R0-proven k_prep (R4's "coalesced zz" ran on 32 blocks =
// 128 waves chipwide -> under-parallel tail; rest-time 151 -> 235 us).
// blocks 0..1023: E rows (ee + Ep permuted-bf16 conversion); 1024..1535: z rows
__global__ __launch_bounds__(256)
void k_prep(const float* __restrict__ z, const float* __restrict__ E,
            float* __restrict__ ee, float* __restrict__ zz,
            u32* __restrict__ gmin, u32* __restrict__ cnt, float* __restrict__ acc,
            ushort_t* __restrict__ Ep) {
    const int t = threadIdx.x;
    const int bid = blockIdx.x;
    if (bid == 0 && t == 0) *acc = 0.0f;
    const int g = t >> 4, s = t & 15;
    const int row = bid * 16 + g;
    const float* p;
    int stride;
    if (row < NE) { p = E + (size_t)row * DIMK; stride = 1; }
    else {
        const int q = row - NE;
        const int b = q >> 10, hw = q & 1023;
        p = z + (size_t)b * BSTR + hw; stride = CSTR;
        if (s == 0) { gmin[q] = 0xFFFFFFFFu; cnt[q] = 0u; }
    }
    // np pairwise sum of squares, 16 lanes/row (bitwise np order via fadd commutativity)
    const int h = s >> 3, j = s & 7;
    const float* pp = p + (size_t)(h * 128 + j) * stride;
    float v = pp[0];
    float r = __fmul_rn(v, v);
    for (int i = 1; i < 16; ++i) {
        v = pp[(size_t)(i * 8) * stride];
        r = __fadd_rn(r, __fmul_rn(v, v));
    }
    r = __fadd_rn(r, __shfl_xor(r, 1, 16));
    r = __fadd_rn(r, __shfl_xor(r, 2, 16));
    r = __fadd_rn(r, __shfl_xor(r, 4, 16));
    r = __fadd_rn(r, __shfl_xor(r, 8, 16));
    if (s == 0) {
        if (row < NE) ee[row] = r;
        else          zz[row - NE] = r;
    }
    if (bid < 1024) {
        // Ep: chunk c = kc*64 + quad*16 + l15 holds bf16 E[bid*16+l15][kc*32+quad*8 .. +7]
#pragma unroll
        for (int i = 0; i < 2; ++i) {
            const int c    = t + i * 256;
            const int kc   = c >> 6;
            const int lane = c & 63;
            const int quad = lane >> 4, l15 = lane & 15;
            const float* src = E + (size_t)(bid * 16 + l15) * DIMK + kc * 32 + quad * 8;
            float4 f0 = *(const float4*)(src);
            float4 f1 = *(const float4*)(src + 4);
            uint4 pk;
            pk.x = pkbf(f0.x, f0.y); pk.y = pkbf(f0.z, f0.w);
            pk.z = pkbf(f1.x, f1.y); pk.w = pkbf(f1.z, f1.w);
            *(uint4*)((char*)Ep + (size_t)bid * 8192 + (size_t)c * 16) = pk;
        }
    }
}

// MFMA filter, R6: exact R3 structure (8 waves x 64x32, 512 thr, distance-1
// bufA/bufB — R4/R5 proved the arch-VGPR budget is a HARD 64 under (512,4):
// any extra register array spills to scratch). One register-neutral change:
// the epilogue's 16 serialized scalar rowthr reads (ordered against ds_min
// atomics on the same array -> 16 exposed LDS round trips/tile/wave) become
// one fresh ds_read_b128 per fi (post-MFMA, pre-own-update). Monotone-safe:
// vector pre is earlier-or-equal -> thresholds looser-or-equal -> winner
// still captured; lmin > pre_early+CMARG => lmin > pre_now => skip safe.
__global__ __launch_bounds__(512, 4)
void k_filter(const float* __restrict__ z, const ushort_t* __restrict__ Ep,
              const float* __restrict__ ee,
              u32* __restrict__ gmin, u32* __restrict__ cnt, u16* __restrict__ cand) {
    __shared__ ushort_t Az[32768];          // 64 KB A store, live across whole sweep
    __shared__ __align__(16) u32 rowthr[128];
    char* lds = (char*)Az;

    const int t     = threadIdx.x;
    const int bid   = blockIdx.x;
    const int chunk = bid & 7;
    const int rb    = bid >> 3;
    const int n0    = rb * 128;
    const int j0c   = chunk * 2048;
    const int b     = n0 >> 10, hw0 = n0 & 1023;
    const int w     = t >> 6, lane = t & 63, quad = lane >> 4, l15 = lane & 15;
    const int wr    = (w >> 2) * 64;        // row-group: waves 0-3 -> rows 0-63, 4-7 -> 64-127
    const int wc    = (w & 3) * 32;         // col-group: 4 groups x 32 cols

    if (t < 128) rowthr[t] = THR_INIT;      // finite sentinel (see THR_INIT note)

    // ---- stage A once: z[b][k][hw] -> bf16 LDS [row][k] swizzled (unchanged) ----
    {
        const int rbase = (t & 31) * 4;
        const int ksub  = (t >> 5) * 2;     // 16 values: 0,2,...,30
        for (int p = 0; p < 8; ++p) {
            const int k0 = p * 32 + ksub;
            float4 f0 = *(const float4*)(z + (size_t)b * BSTR + (size_t)k0 * CSTR + hw0 + rbase);
            float4 f1 = *(const float4*)(z + (size_t)b * BSTR + (size_t)(k0 + 1) * CSTR + hw0 + rbase);
            const float a0[4] = {f0.x, f0.y, f0.z, f0.w};
            const float a1[4] = {f1.x, f1.y, f1.z, f1.w};
#pragma unroll
            for (int i = 0; i < 4; ++i) {
                const int row = rbase + i;
                *(u32*)(lds + row * 512 + ((k0 * 2) ^ ((row & 7) << 4))) = pkbf(a0[i], a1[i]);
            }
        }
    }
    __syncthreads();   // only barrier — sweep below is barrier-free; Az persists

    // per-wave A row addressing (fi-indexed, fully unrolled -> static)
    int aoff[4], aswz[4];
#pragma unroll
    for (int fi = 0; fi < 4; ++fi) {
        const int row = wr + fi * 16 + l15;
        aoff[fi] = row * 512;
        aswz[fi] = (row & 7) << 4;
    }

    const int cbase = (j0c + wc) >> 4;   // 16-col group index of fj=0, tile 0 ref
    const size_t lofs = (size_t)lane * 8;

    bf16x8 bufA[2], bufB[2];
#define LOADB(dst, ct, kc)                                                        \
    {                                                                             \
        const int bg = cbase + (ct) * 8;                                          \
        const size_t ko = (size_t)((kc) * 64) * 8 + lofs;                         \
        _Pragma("unroll")                                                         \
        for (int fj = 0; fj < 2; ++fj)                                            \
            dst[fj] = *(const bf16x8*)(Ep + (size_t)(bg + fj) * 4096 + ko);       \
    }

    LOADB(bufA, 0, 0);   // prime the pipeline

    // sweep tiles; it==16 re-visits tile 0 with tight thresholds (bootstrap)
    for (int it = 0; it <= 16; ++it) {
        const int ct = (it == 16) ? 0 : it;
        const bool collect = (it > 0);
        const int j0 = j0c + ct * 128;

        float eev[2];
#pragma unroll
        for (int fj = 0; fj < 2; ++fj) eev[fj] = ee[j0 + wc + fj * 16 + l15];

        f32x4 acc[4][2];
#pragma unroll
        for (int fi = 0; fi < 4; ++fi)
#pragma unroll
            for (int fj = 0; fj < 2; ++fj)
#pragma unroll
                for (int r = 0; r < 4; ++r) acc[fi][fj][r] = 0.0f;

#pragma unroll
        for (int kc = 0; kc < 8; ++kc) {
            // issue next buffer's loads BEFORE consuming current (stay in flight)
            int nit = it, nkc = kc + 1;
            if (nkc == 8) { nkc = 0; nit = it + 1; }
            const int nct = (nit >= 16) ? 0 : nit;
            // A fragments for this kc from LDS (4x ds_read_b128, 2-way conflict = free)
            bf16x8 afk[4];
#pragma unroll
            for (int fi = 0; fi < 4; ++fi)
                afk[fi] = *(const bf16x8*)(lds + aoff[fi] + ((kc * 64 + quad * 16) ^ aswz[fi]));
            if (kc & 1) {
                LOADB(bufA, nct, nkc);
#pragma unroll
                for (int fi = 0; fi < 4; ++fi)
#pragma unroll
                    for (int fj = 0; fj < 2; ++fj)
                        acc[fi][fj] = __builtin_amdgcn_mfma_f32_16x16x32_bf16(
                            afk[fi], bufB[fj], acc[fi][fj], 0, 0, 0);
            } else {
                LOADB(bufB, nct, nkc);
#pragma unroll
                for (int fi = 0; fi < 4; ++fi)
#pragma unroll
                    for (int fj = 0; fj < 2; ++fj)
                        acc[fi][fj] = __builtin_amdgcn_mfma_f32_16x16x32_bf16(
                            afk[fi], bufA[fj], acc[fi][fj], 0, 0, 0);
            }
        }

        // ---- any-skip epilogue: v = ee - 2*dot; one fresh b128 rowthr read per fi ----
#pragma unroll
        for (int fi = 0; fi < 4; ++fi) {
            // fresh post-MFMA vector read of this fi's 4 row thresholds
            const uint4 tq = *(const uint4*)&rowthr[wr + fi * 16 + quad * 4];
            const u32 preq[4] = {tq.x, tq.y, tq.z, tq.w};
#pragma unroll
            for (int r = 0; r < 4; ++r) {
                const float vv0 = fmaf(-2.0f, acc[fi][0][r], eev[0]);
                const float vv1 = fmaf(-2.0f, acc[fi][1][r], eev[1]);
                const float lmin = fminf(vv0, vv1);
                const int rl = wr + fi * 16 + quad * 4 + r;
                const u32 pre = preq[r];                    // earlier-or-equal history
                const float thr = funmap(pre) + CMARG;      // finite (THR_INIT sentinel)
                // skip-safe: no lane <= thr => no collect AND wave-min > pre (atomic no-op)
                if (__any(lmin <= thr)) {
                    float m = lmin;
                    m = fminf(m, __shfl_xor(m, 1, 16));
                    m = fminf(m, __shfl_xor(m, 2, 16));
                    m = fminf(m, __shfl_xor(m, 4, 16));
                    m = fminf(m, __shfl_xor(m, 8, 16));
                    if (l15 == 0) atomicMin(&rowthr[rl], fmap(m));
                    if (collect) {
                        // pre >= global row min => thr complete for the np winner
                        const int rg = n0 + rl;
                        if (vv0 <= thr) {
                            u32 p = atomicAdd(&cnt[rg], 1u);
                            if (p < SLOTS)
                                cand[(size_t)rg * SLOTS + p] = (u16)(j0 + wc + l15);
                        }
                        if (vv1 <= thr) {
                            u32 p = atomicAdd(&cnt[rg], 1u);
                            if (p < SLOTS)
                                cand[(size_t)rg * SLOTS + p] = (u16)(j0 + wc + 16 + l15);
                        }
                    }
                }
            }
        }
        // every-tile cross-chunk threshold exchange (R0-exact: monotone-safe, no barrier)
        if (t < 128) {
            const u32 lv = rowthr[t];
            const u32 old = atomicMin(&gmin[n0 + t], lv);
            if (old < lv) atomicMin(&rowthr[t], old);
        }
    }
#undef LOADB
}

// numpy-bitwise rescore of ALL collected candidates (winner provably in set)
__global__ __launch_bounds__(64)
void k_rescore(const float* __restrict__ z, const float* __restrict__ E,
               const float* __restrict__ zz, const float* __restrict__ ee,
               const u32* __restrict__ cnt, const u16* __restrict__ cand,
               float* __restrict__ out_idx) {
    const int q = blockIdx.x;
    const int t = threadIdx.x;
    const int b = q >> 10, hw = q & 1023;
    const u32 n = min(cnt[q], (u32)SLOTS);

    u64 best = 0xFFFFFFFFFFFFFFFFULL;
#pragma unroll
    for (int s = 0; s < 2; ++s) {
        const u32 slot = (u32)t + s * 64;
        if (slot < n) {
            const int j = (int)cand[(size_t)q * SLOTS + slot] & (NE - 1);   // OOB-proof
            const float ze = np_einsum_dot(z + (size_t)b * BSTR + hw, CSTR, E + (size_t)j * DIMK);
            const float t1 = __fadd_rn(zz[q], ee[j]);
            const float d  = __fsub_rn(t1, __fmul_rn(2.0f, ze));
            u64 key = ((u64)fmap(d) << 32) | (u32)j;   // ties -> lowest j
            if (key < best) best = key;
        }
    }
#pragma unroll
    for (int off = 1; off < 64; off <<= 1) {
        u64 o = __shfl_xor(best, off, 64);
        if (o < best) best = o;
    }
    if (t == 0) out_idx[q] = (float)((int)(best & 0xFFFFFFFFULL) & (NE - 1));
}

// R6: FULL REVERT to the R0-proven k_finalize (gather + transpose + loss;
// 256 blocks = 32 q-groups x 8 c-groups).
__global__ __launch_bounds__(256)
void k_finalize(const float* __restrict__ z, const float* __restrict__ E,
                const float* __restrict__ out_idx,
                float* __restrict__ out0, float* __restrict__ acc) {
    __shared__ float T[256 * 33];
    __shared__ float red[256];
    const int t  = threadIdx.x;
    const int qg = blockIdx.x >> 3;
    const int ch = blockIdx.x & 7;
    const int q0 = qg * 256;
    const int c0 = ch * 32;
    const int b  = q0 >> 10, hw0 = q0 & 1023;
    const int idx = ((int)out_idx[q0 + t]) & (NE - 1);
    const float* er = E + (size_t)idx * DIMK + c0;
#pragma unroll
    for (int i = 0; i < 8; ++i) {
        float4 f = *(const float4*)(er + i * 4);
        T[t * 33 + i * 4 + 0] = f.x;
        T[t * 33 + i * 4 + 1] = f.y;
        T[t * 33 + i * 4 + 2] = f.z;
        T[t * 33 + i * 4 + 3] = f.w;
    }
    __syncthreads();
    float ls = 0.0f;
#pragma unroll 4
    for (int cc = 0; cc < 32; ++cc) {
        // output (c0+cc, hw0+t) gets row q=hw0+t's embedding value, from T[t][cc]
        const float ev = T[t * 33 + cc];
        const size_t o = (size_t)b * BSTR + (size_t)(c0 + cc) * CSTR + hw0 + t;
        const float d = ev - z[o];
        ls = fmaf(d, d, ls);
        out0[o] = ev;
    }
    red[t] = ls;
    __syncthreads();
    for (int s = 128; s > 0; s >>= 1) {
        if (t < s) red[t] += red[t + s];
        __syncthreads();
    }
    if (t == 0) atomicAdd(acc, red[0]);
}

__global__ void k_loss(const float* __restrict__ acc, float* __restrict__ out_loss) {
    *out_loss = 1.25f * (*acc) * (1.0f / 2097152.0f);
}

extern "C" void kernel_launch(void* const* d_in, const int* in_sizes, int n_in,
                              void* d_out, int out_size, void* d_ws, size_t ws_size,
                              hipStream_t stream) {
    const float* z = (const float*)d_in[0];   // [8,256,32,32] fp32
    const float* E = (const float*)d_in[1];   // [16384,256] fp32

    float* out0     = (float*)d_out;
    float* out_loss = (float*)d_out + 2097152;
    float* out_idx  = (float*)d_out + 2097153;

    float*    acc  = (float*)d_ws;
    float*    ee   = (float*)((char*)d_ws + WS_EE);
    float*    zz   = (float*)((char*)d_ws + WS_ZZ);
    u32*      gmin = (u32*)  ((char*)d_ws + WS_GMIN);
    u32*      cnt  = (u32*)  ((char*)d_ws + WS_CNT);
    u16*      cand = (u16*)  ((char*)d_ws + WS_CAND);
    ushort_t* Ep   = (ushort_t*)((char*)d_ws + WS_EP);

    k_prep<<<1536, 256, 0, stream>>>(z, E, ee, zz, gmin, cnt, acc, Ep);
    k_filter<<<512, 512, 0, stream>>>(z, Ep, ee, gmin, cnt, cand);
    k_rescore<<<NQ, 64, 0, stream>>>(z, E, zz, ee, cnt, cand, out_idx);
    k_finalize<<<256, 256, 0, stream>>>(z, E, out_idx, out0, acc);
    k_loss<<<1, 1, 0, stream>>>(acc, out_loss);
}